// Round 4
// baseline (516.084 us; speedup 1.0000x reference)
//
#include <hip/hip_runtime.h>
#include <hip/hip_bf16.h>

#define EPSN 1e-12f
#define EPSL 1e-10f
#define KSPLIT 16
#define KS 64

typedef __attribute__((ext_vector_type(8))) short short8;
typedef __attribute__((ext_vector_type(4))) float f32x4;

__device__ __forceinline__ unsigned short f2bf_rne(float f) {
  union { float f; unsigned u; } x; x.f = f;
  unsigned r = x.u + 0x7FFFu + ((x.u >> 16) & 1u);
  return (unsigned short)(r >> 16);
}

// Kernel 1: per-row prep. One wave per row (D=128, 2 elems/lane).
// e = x / max(||x||_4, eps)  (fp32, row-major)
// lpB = bf16(log(e+eps)) in MFMA B-fragment order:
//   element (d, k): frag f = (k>>5)*8 + (d>>4), lane = (d&15) + 16*((k>>3)&3),
//   ushort index = f*512 + lane*8 + (k&7)  -> each frag is a contiguous 1KB block.
__global__ __launch_bounds__(256)
void prep_kernel(const float* __restrict__ emb, float* __restrict__ e,
                 unsigned short* __restrict__ lpB, float* __restrict__ plp,
                 float* __restrict__ S, float* __restrict__ v, int N) {
  int w = threadIdx.x >> 6, l = threadIdx.x & 63;
  int row = blockIdx.x * 4 + w;
  if (row >= N) return;
  const float* x = emb + (size_t)row * 128;
  float2 xv = *(const float2*)(x + 2 * l);
  float s4 = xv.x*xv.x*xv.x*xv.x + xv.y*xv.y*xv.y*xv.y;
  #pragma unroll
  for (int m = 1; m < 64; m <<= 1) s4 += __shfl_xor(s4, m);
  float denom = fmaxf(sqrtf(sqrtf(s4)), EPSN);
  float e0 = xv.x / denom, e1 = xv.y / denom;
  float lp0 = logf(e0 + EPSL), lp1 = logf(e1 + EPSL);
  e[(size_t)row * 128 + 2*l]     = e0;
  e[(size_t)row * 128 + 2*l + 1] = e1;
  int ksr = row >> 5, lhir = (row >> 3) & 3, jr = row & 7;
  int d0 = 2 * l, d1 = 2 * l + 1;
  lpB[((size_t)(ksr*8 + (d0>>4))*64 + (d0&15) + 16*lhir)*8 + jr] = f2bf_rne(lp0);
  lpB[((size_t)(ksr*8 + (d1>>4))*64 + (d1&15) + 16*lhir)*8 + jr] = f2bf_rne(lp1);
  float pl = e0 * lp0 + e1 * lp1;
  #pragma unroll
  for (int m = 1; m < 64; m <<= 1) pl += __shfl_xor(pl, m);
  if (l == 0) { plp[row] = pl; S[row] = 0.f; v[row] = 0.f; }
}

// Kernel 2: fused GEMM M = adj @ log_p, 12-iter K-loop, LDS-double-buffered B
// (reg-staged, issue-early/write-late), direct-to-reg A with ~2-iter prefetch,
// raw barriers with lgkmcnt(0) only (global loads stay in flight across them).
__global__ __launch_bounds__(256, 3)
void gemm_kernel(const float* __restrict__ adj, const float* __restrict__ e,
                 const unsigned short* __restrict__ lpB,
                 float* __restrict__ S, float* __restrict__ v, int N) {
  __shared__ unsigned short bsh[2][KS * 128];  // 2 x 16KB (64k x 128d bf16)
  int w = threadIdx.x >> 6, l = threadIdx.x & 63;
  int l16 = l & 15, lhi = l >> 4;
  int wrow0 = blockIdx.x * 128 + w * 32;
  int kr = N / KSPLIT;          // 768
  int k0 = blockIdx.y * kr;
  int nt = kr / KS;             // 12 (even)

  f32x4 acc[2][8];
  #pragma unroll
  for (int i = 0; i < 2; ++i)
    #pragma unroll
    for (int j = 0; j < 8; ++j) acc[i][j] = (f32x4){0.f, 0.f, 0.f, 0.f};
  float sAcc[2] = {0.f, 0.f};

  // A: lane (l16,lhi) reads rows wrow0+l16 / +16, k = k0+t*64+ks*32+lhi*8 (2x float4)
  const float* rp0 = adj + (size_t)(wrow0 + l16) * N + k0 + lhi * 8;
  const float* rp1 = rp0 + (size_t)16 * N;

  float4 aset0[2][2][2], aset1[2][2][2];
  float4 rBs[2][4];

#define LOADA(buf, t)                                                   \
  {                                                                     \
    _Pragma("unroll")                                                   \
    for (int rt_ = 0; rt_ < 2; ++rt_) {                                 \
      const float* bp_ = (rt_ ? rp1 : rp0) + (t) * KS;                  \
      _Pragma("unroll")                                                 \
      for (int ks_ = 0; ks_ < 2; ++ks_) {                               \
        buf[rt_][ks_][0] = *(const float4*)(bp_ + ks_ * 32);            \
        buf[rt_][ks_][1] = *(const float4*)(bp_ + ks_ * 32 + 4);        \
      }                                                                 \
    }                                                                   \
  }

  // B chunk t = 16KB contiguous (frag-major); wave w stages bytes [w*4K, +4K)
#define LOADB(dst, t)                                                   \
  {                                                                     \
    const char* p_ = (const char*)lpB + (((size_t)(k0 + (t) * KS)) << 8) \
                     + w * 4096 + l * 16;                               \
    _Pragma("unroll")                                                   \
    for (int i_ = 0; i_ < 4; ++i_)                                      \
      dst[i_] = *(const float4*)(p_ + i_ * 1024);                       \
  }

#define WRITEB(bi, src)                                                 \
  {                                                                     \
    char* q_ = (char*)bsh[bi] + w * 4096 + l * 16;                      \
    _Pragma("unroll")                                                   \
    for (int i_ = 0; i_ < 4; ++i_)                                      \
      *(float4*)(q_ + i_ * 1024) = src[i_];                             \
  }

#define STEP(abuf, bi)                                                  \
  {                                                                     \
    _Pragma("unroll")                                                   \
    for (int ks_ = 0; ks_ < 2; ++ks_) {                                 \
      short8 bb_[8];                                                    \
      _Pragma("unroll")                                                 \
      for (int ct_ = 0; ct_ < 8; ++ct_)                                 \
        bb_[ct_] = *(const short8*)((char*)bsh[bi] + (ks_*8 + ct_)*1024 + l*16); \
      short8 af_[2];                                                    \
      _Pragma("unroll")                                                 \
      for (int rt_ = 0; rt_ < 2; ++rt_) {                               \
        float4 x0_ = abuf[rt_][ks_][0], x1_ = abuf[rt_][ks_][1];        \
        sAcc[rt_] += ((x0_.x + x0_.y) + (x0_.z + x0_.w)) +              \
                     ((x1_.x + x1_.y) + (x1_.z + x1_.w));               \
        short8 t_;                                                      \
        t_[0] = (short)f2bf_rne(x0_.x); t_[1] = (short)f2bf_rne(x0_.y); \
        t_[2] = (short)f2bf_rne(x0_.z); t_[3] = (short)f2bf_rne(x0_.w); \
        t_[4] = (short)f2bf_rne(x1_.x); t_[5] = (short)f2bf_rne(x1_.y); \
        t_[6] = (short)f2bf_rne(x1_.z); t_[7] = (short)f2bf_rne(x1_.w); \
        af_[rt_] = t_;                                                  \
      }                                                                 \
      __builtin_amdgcn_s_setprio(1);                                    \
      _Pragma("unroll")                                                 \
      for (int ct_ = 0; ct_ < 8; ++ct_) {                               \
        acc[0][ct_] = __builtin_amdgcn_mfma_f32_16x16x32_bf16(af_[0], bb_[ct_], acc[0][ct_], 0, 0, 0); \
        acc[1][ct_] = __builtin_amdgcn_mfma_f32_16x16x32_bf16(af_[1], bb_[ct_], acc[1][ct_], 0, 0, 0); \
      }                                                                 \
      __builtin_amdgcn_s_setprio(0);                                    \
    }                                                                   \
  }

#define FENCE_BARRIER()                                                 \
  {                                                                     \
    asm volatile("s_waitcnt lgkmcnt(0)" ::: "memory");                  \
    __builtin_amdgcn_s_barrier();                                       \
    asm volatile("" ::: "memory");                                      \
  }

  // iter t: read buf(t&1) + MFMA A(t); write B(t+1) -> buf(t&1^1);
  // issue loads of B(t+2)/A(t+2); lgkm-drain; barrier.
#define ITER(t, aset, bi)                                               \
  {                                                                     \
    STEP(aset, bi);                                                     \
    if ((t) + 1 < nt) WRITEB((bi) ^ 1, rBs[((t) + 1) & 1]);             \
    if ((t) + 2 < nt) { LOADB(rBs[(t) & 1], (t) + 2); LOADA(aset, (t) + 2); } \
    FENCE_BARRIER();                                                    \
  }

  // prologue: B(0),A(0),B(1),A(1) in flight; buf0 <- B(0)
  LOADB(rBs[0], 0);
  LOADA(aset0, 0);
  LOADB(rBs[1], 1);
  LOADA(aset1, 1);
  WRITEB(0, rBs[0]);
  FENCE_BARRIER();

  for (int t = 0; t < nt; t += 2) {
    ITER(t, aset0, 0);
    ITER(t + 1, aset1, 1);
  }

  // adj rowsum partials: lane (l16,lhi) holds row (wrow0+rt*16+l16)'s lhi-slice.
  #pragma unroll
  for (int rt = 0; rt < 2; ++rt) {
    float s = sAcc[rt];
    s += __shfl_xor(s, 16);
    s += __shfl_xor(s, 32);
    if (l < 16) atomicAdd(&S[wrow0 + rt * 16 + l], s);
  }

  // v[i] += sum_d e[i,d] * C_part[i,d]; C layout: col=lane&15, row=(lane>>4)*4+reg.
  #pragma unroll
  for (int rt = 0; rt < 2; ++rt) {
    #pragma unroll
    for (int r = 0; r < 4; ++r) {
      int row = wrow0 + rt * 16 + lhi * 4 + r;
      float p = 0.f;
      #pragma unroll
      for (int ct = 0; ct < 8; ++ct)
        p += e[(size_t)row * 128 + ct * 16 + l16] * acc[rt][ct][r];
      p += __shfl_xor(p, 1);
      p += __shfl_xor(p, 2);
      p += __shfl_xor(p, 4);
      p += __shfl_xor(p, 8);
      if (l16 == 0) atomicAdd(&v[row], p);
    }
  }
}

// Kernel 3: out = lambda * sum_i [ plp[i]*(S_i/max(S_i,eps)) - v[i]/max(S_i,eps) ]
__global__ __launch_bounds__(1024)
void final_kernel(const float* __restrict__ plp, const float* __restrict__ S,
                  const float* __restrict__ v, const float* __restrict__ lam,
                  float* __restrict__ out, int N) {
  __shared__ float red[16];
  float acc = 0.f;
  for (int i = threadIdx.x; i < N; i += 1024) {
    float s = S[i], d = fmaxf(s, EPSN);
    acc += plp[i] * (s / d) - v[i] / d;
  }
  #pragma unroll
  for (int m = 1; m < 64; m <<= 1) acc += __shfl_xor(acc, m);
  int w = threadIdx.x >> 6, l = threadIdx.x & 63;
  if (l == 0) red[w] = acc;
  __syncthreads();
  if (threadIdx.x == 0) {
    float t = 0.f;
    #pragma unroll
    for (int i = 0; i < 16; ++i) t += red[i];
    out[0] = lam[0] * t;
  }
}

extern "C" void kernel_launch(void* const* d_in, const int* in_sizes, int n_in,
                              void* d_out, int out_size, void* d_ws, size_t ws_size,
                              hipStream_t stream) {
  const float* emb = (const float*)d_in[0];
  const float* adj = (const float*)d_in[1];
  const float* lam = (const float*)d_in[2];
  int N = in_sizes[0] / 128;  // D = 128 per reference

  char* ws = (char*)d_ws;
  float* e            = (float*)ws;                                 // N*128 f32
  unsigned short* lpB = (unsigned short*)(ws + (size_t)N * 512);    // N*128 bf16, fragment order
  float* plp          = (float*)(ws + (size_t)N * 768);             // N f32
  float* S            = plp + N;                                    // N f32
  float* v            = S + N;                                      // N f32

  prep_kernel<<<(N + 3) / 4, 256, 0, stream>>>(emb, e, lpB, plp, S, v, N);
  dim3 grid(N / 128, KSPLIT);
  gemm_kernel<<<grid, 256, 0, stream>>>(adj, e, lpB, S, v, N);
  final_kernel<<<1, 1024, 0, stream>>>(plp, S, v, lam, (float*)d_out, N);
}

// Round 5
// 247.182 us; speedup vs baseline: 2.0879x; 2.0879x over previous
//
#include <hip/hip_runtime.h>
#include <hip/hip_bf16.h>

#define EPSN 1e-12f
#define EPSL 1e-10f
#define KSPLIT 16
#define KS 64

typedef __attribute__((ext_vector_type(8))) short short8;
typedef __attribute__((ext_vector_type(4))) float f32x4;

__device__ __forceinline__ unsigned short f2bf_rne(float f) {
  union { float f; unsigned u; } x; x.f = f;
  unsigned r = x.u + 0x7FFFu + ((x.u >> 16) & 1u);
  return (unsigned short)(r >> 16);
}

// Kernel 1: per-row prep. One wave per row (D=128, 2 elems/lane).
// e = x / max(||x||_4, eps)  (fp32, row-major)
// lpB = bf16(log(e+eps)) in MFMA B-fragment order:
//   element (d, k): frag f = (k>>5)*8 + (d>>4), lane = (d&15) + 16*((k>>3)&3),
//   ushort index = f*512 + lane*8 + (k&7)  -> each frag is a contiguous 1KB block.
__global__ __launch_bounds__(256)
void prep_kernel(const float* __restrict__ emb, float* __restrict__ e,
                 unsigned short* __restrict__ lpB, float* __restrict__ plp,
                 float* __restrict__ S, float* __restrict__ v, int N) {
  int w = threadIdx.x >> 6, l = threadIdx.x & 63;
  int row = blockIdx.x * 4 + w;
  if (row >= N) return;
  const float* x = emb + (size_t)row * 128;
  float2 xv = *(const float2*)(x + 2 * l);
  float s4 = xv.x*xv.x*xv.x*xv.x + xv.y*xv.y*xv.y*xv.y;
  #pragma unroll
  for (int m = 1; m < 64; m <<= 1) s4 += __shfl_xor(s4, m);
  float denom = fmaxf(sqrtf(sqrtf(s4)), EPSN);
  float e0 = xv.x / denom, e1 = xv.y / denom;
  float lp0 = logf(e0 + EPSL), lp1 = logf(e1 + EPSL);
  e[(size_t)row * 128 + 2*l]     = e0;
  e[(size_t)row * 128 + 2*l + 1] = e1;
  int ksr = row >> 5, lhir = (row >> 3) & 3, jr = row & 7;
  int d0 = 2 * l, d1 = 2 * l + 1;
  lpB[((size_t)(ksr*8 + (d0>>4))*64 + (d0&15) + 16*lhir)*8 + jr] = f2bf_rne(lp0);
  lpB[((size_t)(ksr*8 + (d1>>4))*64 + (d1&15) + 16*lhir)*8 + jr] = f2bf_rne(lp1);
  float pl = e0 * lp0 + e1 * lp1;
  #pragma unroll
  for (int m = 1; m < 64; m <<= 1) pl += __shfl_xor(pl, m);
  if (l == 0) { plp[row] = pl; S[row] = 0.f; v[row] = 0.f; }
}

// Kernel 2: fused GEMM M = adj @ log_p, 12-iter K-loop, LDS-double-buffered B
// (reg-staged, issue-early/write-late), direct-to-reg A with 2-iter prefetch.
// ALL register arrays statically indexed (named rB0/rB1, aset0/aset1) — rule #20.
__global__ __launch_bounds__(256, 2)
void gemm_kernel(const float* __restrict__ adj, const float* __restrict__ e,
                 const unsigned short* __restrict__ lpB,
                 float* __restrict__ S, float* __restrict__ v, int N) {
  __shared__ unsigned short bsh[2][KS * 128];  // 2 x 16KB (64k x 128d bf16)
  int w = threadIdx.x >> 6, l = threadIdx.x & 63;
  int l16 = l & 15, lhi = l >> 4;
  int wrow0 = blockIdx.x * 128 + w * 32;
  int kr = N / KSPLIT;          // 768
  int k0 = blockIdx.y * kr;
  int nt = kr / KS;             // 12 (even)

  f32x4 acc[2][8];
  #pragma unroll
  for (int i = 0; i < 2; ++i)
    #pragma unroll
    for (int j = 0; j < 8; ++j) acc[i][j] = (f32x4){0.f, 0.f, 0.f, 0.f};
  float sAcc[2] = {0.f, 0.f};

  // A: lane (l16,lhi) reads rows wrow0+l16 / +16, k = k0+t*64+ks*32+lhi*8 (2x float4)
  const float* rp0 = adj + (size_t)(wrow0 + l16) * N + k0 + lhi * 8;
  const float* rp1 = rp0 + (size_t)16 * N;

  float4 aset0[2][2][2], aset1[2][2][2];
  float4 rB0[4], rB1[4];

#define LOADA(buf, t)                                                   \
  {                                                                     \
    _Pragma("unroll")                                                   \
    for (int rt_ = 0; rt_ < 2; ++rt_) {                                 \
      const float* bp_ = (rt_ ? rp1 : rp0) + (t) * KS;                  \
      _Pragma("unroll")                                                 \
      for (int ks_ = 0; ks_ < 2; ++ks_) {                               \
        buf[rt_][ks_][0] = *(const float4*)(bp_ + ks_ * 32);            \
        buf[rt_][ks_][1] = *(const float4*)(bp_ + ks_ * 32 + 4);        \
      }                                                                 \
    }                                                                   \
  }

  // B chunk t = 16KB contiguous (frag-major); wave w stages bytes [w*4K, +4K)
#define LOADB(dst, t)                                                   \
  {                                                                     \
    const char* p_ = (const char*)lpB + (((size_t)(k0 + (t) * KS)) << 8) \
                     + w * 4096 + l * 16;                               \
    _Pragma("unroll")                                                   \
    for (int i_ = 0; i_ < 4; ++i_)                                      \
      dst[i_] = *(const float4*)(p_ + i_ * 1024);                       \
  }

#define WRITEB(bi, src)                                                 \
  {                                                                     \
    char* q_ = (char*)bsh[bi] + w * 4096 + l * 16;                      \
    _Pragma("unroll")                                                   \
    for (int i_ = 0; i_ < 4; ++i_)                                      \
      *(float4*)(q_ + i_ * 1024) = src[i_];                             \
  }

#define STEP(abuf, bi)                                                  \
  {                                                                     \
    _Pragma("unroll")                                                   \
    for (int ks_ = 0; ks_ < 2; ++ks_) {                                 \
      short8 bb_[8];                                                    \
      _Pragma("unroll")                                                 \
      for (int ct_ = 0; ct_ < 8; ++ct_)                                 \
        bb_[ct_] = *(const short8*)((char*)bsh[bi] + (ks_*8 + ct_)*1024 + l*16); \
      short8 af_[2];                                                    \
      _Pragma("unroll")                                                 \
      for (int rt_ = 0; rt_ < 2; ++rt_) {                               \
        float4 x0_ = abuf[rt_][ks_][0], x1_ = abuf[rt_][ks_][1];        \
        sAcc[rt_] += ((x0_.x + x0_.y) + (x0_.z + x0_.w)) +              \
                     ((x1_.x + x1_.y) + (x1_.z + x1_.w));               \
        short8 t_;                                                      \
        t_[0] = (short)f2bf_rne(x0_.x); t_[1] = (short)f2bf_rne(x0_.y); \
        t_[2] = (short)f2bf_rne(x0_.z); t_[3] = (short)f2bf_rne(x0_.w); \
        t_[4] = (short)f2bf_rne(x1_.x); t_[5] = (short)f2bf_rne(x1_.y); \
        t_[6] = (short)f2bf_rne(x1_.z); t_[7] = (short)f2bf_rne(x1_.w); \
        af_[rt_] = t_;                                                  \
      }                                                                 \
      __builtin_amdgcn_s_setprio(1);                                    \
      _Pragma("unroll")                                                 \
      for (int ct_ = 0; ct_ < 8; ++ct_) {                               \
        acc[0][ct_] = __builtin_amdgcn_mfma_f32_16x16x32_bf16(af_[0], bb_[ct_], acc[0][ct_], 0, 0, 0); \
        acc[1][ct_] = __builtin_amdgcn_mfma_f32_16x16x32_bf16(af_[1], bb_[ct_], acc[1][ct_], 0, 0, 0); \
      }                                                                 \
      __builtin_amdgcn_s_setprio(0);                                    \
    }                                                                   \
  }

#define FENCE_BARRIER()                                                 \
  {                                                                     \
    asm volatile("s_waitcnt lgkmcnt(0)" ::: "memory");                  \
    __builtin_amdgcn_s_barrier();                                       \
    asm volatile("" ::: "memory");                                      \
  }

  // prologue: B(0),A(0),B(1),A(1) in flight; lds0 <- B(0)
  LOADB(rB0, 0);
  LOADA(aset0, 0);
  LOADB(rB1, 1);
  LOADA(aset1, 1);
  WRITEB(0, rB0);
  FENCE_BARRIER();

  // Steady state (all buffer choices compile-time):
  //  even t: STEP(aset0, lds0); write B(t+1)=rB1 -> lds1; load B(t+2)->rB0, A(t+2)->aset0
  //  odd  t: STEP(aset1, lds1); write B(t+2)=rB0 -> lds0; load B(t+3)->rB1, A(t+3)->aset1
  for (int t = 0; t < nt; t += 2) {
    STEP(aset0, 0);
    WRITEB(1, rB1);
    if (t + 2 < nt) { LOADB(rB0, t + 2); LOADA(aset0, t + 2); }
    FENCE_BARRIER();

    STEP(aset1, 1);
    if (t + 2 < nt) WRITEB(0, rB0);
    if (t + 3 < nt) { LOADB(rB1, t + 3); LOADA(aset1, t + 3); }
    FENCE_BARRIER();
  }

  // adj rowsum partials: lane (l16,lhi) holds row (wrow0+rt*16+l16)'s lhi-slice.
  #pragma unroll
  for (int rt = 0; rt < 2; ++rt) {
    float s = sAcc[rt];
    s += __shfl_xor(s, 16);
    s += __shfl_xor(s, 32);
    if (l < 16) atomicAdd(&S[wrow0 + rt * 16 + l], s);
  }

  // v[i] += sum_d e[i,d] * C_part[i,d]; C layout: col=lane&15, row=(lane>>4)*4+reg.
  #pragma unroll
  for (int rt = 0; rt < 2; ++rt) {
    #pragma unroll
    for (int r = 0; r < 4; ++r) {
      int row = wrow0 + rt * 16 + lhi * 4 + r;
      float p = 0.f;
      #pragma unroll
      for (int ct = 0; ct < 8; ++ct)
        p += e[(size_t)row * 128 + ct * 16 + l16] * acc[rt][ct][r];
      p += __shfl_xor(p, 1);
      p += __shfl_xor(p, 2);
      p += __shfl_xor(p, 4);
      p += __shfl_xor(p, 8);
      if (l16 == 0) atomicAdd(&v[row], p);
    }
  }
}

// Kernel 3: out = lambda * sum_i [ plp[i]*(S_i/max(S_i,eps)) - v[i]/max(S_i,eps) ]
__global__ __launch_bounds__(1024)
void final_kernel(const float* __restrict__ plp, const float* __restrict__ S,
                  const float* __restrict__ v, const float* __restrict__ lam,
                  float* __restrict__ out, int N) {
  __shared__ float red[16];
  float acc = 0.f;
  for (int i = threadIdx.x; i < N; i += 1024) {
    float s = S[i], d = fmaxf(s, EPSN);
    acc += plp[i] * (s / d) - v[i] / d;
  }
  #pragma unroll
  for (int m = 1; m < 64; m <<= 1) acc += __shfl_xor(acc, m);
  int w = threadIdx.x >> 6, l = threadIdx.x & 63;
  if (l == 0) red[w] = acc;
  __syncthreads();
  if (threadIdx.x == 0) {
    float t = 0.f;
    #pragma unroll
    for (int i = 0; i < 16; ++i) t += red[i];
    out[0] = lam[0] * t;
  }
}

extern "C" void kernel_launch(void* const* d_in, const int* in_sizes, int n_in,
                              void* d_out, int out_size, void* d_ws, size_t ws_size,
                              hipStream_t stream) {
  const float* emb = (const float*)d_in[0];
  const float* adj = (const float*)d_in[1];
  const float* lam = (const float*)d_in[2];
  int N = in_sizes[0] / 128;  // D = 128 per reference

  char* ws = (char*)d_ws;
  float* e            = (float*)ws;                                 // N*128 f32
  unsigned short* lpB = (unsigned short*)(ws + (size_t)N * 512);    // N*128 bf16, fragment order
  float* plp          = (float*)(ws + (size_t)N * 768);             // N f32
  float* S            = plp + N;                                    // N f32
  float* v            = S + N;                                      // N f32

  prep_kernel<<<(N + 3) / 4, 256, 0, stream>>>(emb, e, lpB, plp, S, v, N);
  dim3 grid(N / 128, KSPLIT);
  gemm_kernel<<<grid, 256, 0, stream>>>(adj, e, lpB, S, v, N);
  final_kernel<<<1, 1024, 0, stream>>>(plp, S, v, lam, (float*)d_out, N);
}

// Round 6
// 246.230 us; speedup vs baseline: 2.0959x; 1.0039x over previous
//
#include <hip/hip_runtime.h>
#include <hip/hip_bf16.h>

#define EPSN 1e-12f
#define EPSL 1e-10f
#define KSPLIT 16
#define KS 64

typedef __attribute__((ext_vector_type(8))) short short8;
typedef __attribute__((ext_vector_type(4))) float f32x4;

__device__ __forceinline__ unsigned short f2bf_rne(float f) {
  union { float f; unsigned u; } x; x.f = f;
  unsigned r = x.u + 0x7FFFu + ((x.u >> 16) & 1u);
  return (unsigned short)(r >> 16);
}

// Kernel 1: per-row prep. One wave per row (D=128, 2 elems/lane).
// eC = e = x/max(||x||_4,eps) stored in MFMA C-fragment layout:
//   e[g, d] -> eC[(((g>>4)*8 + (d>>4))*64 + (d&15) + 16*((g>>2)&3))*4 + (g&3)]
//   (each 16-row x 16-col tile = contiguous 1KB, lane-major float4)
// lpB = bf16(log(e+eps)) in MFMA B-fragment order (contiguous 1KB frags).
// plp[row] = sum_d e*log_p; zero S/v.
__global__ __launch_bounds__(256)
void prep_kernel(const float* __restrict__ emb, float* __restrict__ eC,
                 unsigned short* __restrict__ lpB, float* __restrict__ plp,
                 float* __restrict__ S, float* __restrict__ v, int N) {
  int w = threadIdx.x >> 6, l = threadIdx.x & 63;
  int row = blockIdx.x * 4 + w;
  if (row >= N) return;
  const float* x = emb + (size_t)row * 128;
  float2 xv = *(const float2*)(x + 2 * l);
  float s4 = xv.x*xv.x*xv.x*xv.x + xv.y*xv.y*xv.y*xv.y;
  #pragma unroll
  for (int m = 1; m < 64; m <<= 1) s4 += __shfl_xor(s4, m);
  float denom = fmaxf(sqrtf(sqrtf(s4)), EPSN);
  float e0 = xv.x / denom, e1 = xv.y / denom;
  float lp0 = logf(e0 + EPSL), lp1 = logf(e1 + EPSL);
  // eC (C-fragment layout) writes
  int Rg = row >> 4, lhig = (row >> 2) & 3, rg = row & 3;
  int d0 = 2 * l, d1 = 2 * l + 1;
  eC[(((size_t)Rg * 8 + (d0 >> 4)) * 64 + (d0 & 15) + 16 * lhig) * 4 + rg] = e0;
  eC[(((size_t)Rg * 8 + (d1 >> 4)) * 64 + (d1 & 15) + 16 * lhig) * 4 + rg] = e1;
  // lpB (B-fragment layout) writes
  int ksr = row >> 5, lhir = (row >> 3) & 3, jr = row & 7;
  lpB[((size_t)(ksr*8 + (d0>>4))*64 + (d0&15) + 16*lhir)*8 + jr] = f2bf_rne(lp0);
  lpB[((size_t)(ksr*8 + (d1>>4))*64 + (d1&15) + 16*lhir)*8 + jr] = f2bf_rne(lp1);
  float pl = e0 * lp0 + e1 * lp1;
  #pragma unroll
  for (int m = 1; m < 64; m <<= 1) pl += __shfl_xor(pl, m);
  if (l == 0) { plp[row] = pl; S[row] = 0.f; v[row] = 0.f; }
}

// Kernel 2: fused GEMM M = adj @ log_p, 12-iter K-loop.
// B: global->reg (2-iter residence) -> LDS dbuf (write 2 iters after load).
// A: global->reg, consumed 2 iters after load. All reg arrays statically named.
__global__ __launch_bounds__(256, 2)
void gemm_kernel(const float* __restrict__ adj, const float* __restrict__ eC,
                 const unsigned short* __restrict__ lpB,
                 float* __restrict__ S, float* __restrict__ v, int N) {
  __shared__ unsigned short bsh[2][KS * 128];  // 2 x 16KB (64k x 128d bf16)
  int w = threadIdx.x >> 6, l = threadIdx.x & 63;
  int l16 = l & 15, lhi = l >> 4;
  int wrow0 = blockIdx.x * 128 + w * 32;
  int kr = N / KSPLIT;          // 768
  int k0 = blockIdx.y * kr;
  int nt = kr / KS;             // 12 (even)

  f32x4 acc[2][8];
  #pragma unroll
  for (int i = 0; i < 2; ++i)
    #pragma unroll
    for (int j = 0; j < 8; ++j) acc[i][j] = (f32x4){0.f, 0.f, 0.f, 0.f};
  float sAcc[2] = {0.f, 0.f};

  const float* rp0 = adj + (size_t)(wrow0 + l16) * N + k0 + lhi * 8;
  const float* rp1 = rp0 + (size_t)16 * N;

  float4 aset0[2][2][2], aset1[2][2][2];
  float4 rB0[4], rB1[4];

#define LOADA(buf, t)                                                   \
  {                                                                     \
    _Pragma("unroll")                                                   \
    for (int rt_ = 0; rt_ < 2; ++rt_) {                                 \
      const float* bp_ = (rt_ ? rp1 : rp0) + (t) * KS;                  \
      _Pragma("unroll")                                                 \
      for (int ks_ = 0; ks_ < 2; ++ks_) {                               \
        buf[rt_][ks_][0] = *(const float4*)(bp_ + ks_ * 32);            \
        buf[rt_][ks_][1] = *(const float4*)(bp_ + ks_ * 32 + 4);        \
      }                                                                 \
    }                                                                   \
  }

#define LOADB(dst, t)                                                   \
  {                                                                     \
    const char* p_ = (const char*)lpB + (((size_t)(k0 + (t) * KS)) << 8) \
                     + w * 4096 + l * 16;                               \
    _Pragma("unroll")                                                   \
    for (int i_ = 0; i_ < 4; ++i_)                                      \
      dst[i_] = *(const float4*)(p_ + i_ * 1024);                       \
  }

#define WRITEB(bi, src)                                                 \
  {                                                                     \
    char* q_ = (char*)bsh[bi] + w * 4096 + l * 16;                      \
    _Pragma("unroll")                                                   \
    for (int i_ = 0; i_ < 4; ++i_)                                      \
      *(float4*)(q_ + i_ * 1024) = src[i_];                             \
  }

#define STEP(abuf, bi)                                                  \
  {                                                                     \
    _Pragma("unroll")                                                   \
    for (int ks_ = 0; ks_ < 2; ++ks_) {                                 \
      short8 bb_[8];                                                    \
      _Pragma("unroll")                                                 \
      for (int ct_ = 0; ct_ < 8; ++ct_)                                 \
        bb_[ct_] = *(const short8*)((char*)bsh[bi] + (ks_*8 + ct_)*1024 + l*16); \
      short8 af_[2];                                                    \
      _Pragma("unroll")                                                 \
      for (int rt_ = 0; rt_ < 2; ++rt_) {                               \
        float4 x0_ = abuf[rt_][ks_][0], x1_ = abuf[rt_][ks_][1];        \
        sAcc[rt_] += ((x0_.x + x0_.y) + (x0_.z + x0_.w)) +              \
                     ((x1_.x + x1_.y) + (x1_.z + x1_.w));               \
        short8 t_;                                                      \
        t_[0] = (short)f2bf_rne(x0_.x); t_[1] = (short)f2bf_rne(x0_.y); \
        t_[2] = (short)f2bf_rne(x0_.z); t_[3] = (short)f2bf_rne(x0_.w); \
        t_[4] = (short)f2bf_rne(x1_.x); t_[5] = (short)f2bf_rne(x1_.y); \
        t_[6] = (short)f2bf_rne(x1_.z); t_[7] = (short)f2bf_rne(x1_.w); \
        af_[rt_] = t_;                                                  \
      }                                                                 \
      __builtin_amdgcn_s_setprio(1);                                    \
      _Pragma("unroll")                                                 \
      for (int ct_ = 0; ct_ < 8; ++ct_) {                               \
        acc[0][ct_] = __builtin_amdgcn_mfma_f32_16x16x32_bf16(af_[0], bb_[ct_], acc[0][ct_], 0, 0, 0); \
        acc[1][ct_] = __builtin_amdgcn_mfma_f32_16x16x32_bf16(af_[1], bb_[ct_], acc[1][ct_], 0, 0, 0); \
      }                                                                 \
      __builtin_amdgcn_s_setprio(0);                                    \
    }                                                                   \
  }

#define FENCE_BARRIER()                                                 \
  {                                                                     \
    asm volatile("s_waitcnt lgkmcnt(0)" ::: "memory");                  \
    __builtin_amdgcn_s_barrier();                                       \
    asm volatile("" ::: "memory");                                      \
  }

  // Iter t (even, rB0 / odd, rB1): rB holds tile t+1 (loaded at t-2).
  //   WRITEB(buf[(t+1)&1], rB) -> LOADB(rB, t+3) -> STEP(aset, buf[t&1])
  //   -> LOADA(aset, t+2) -> fence.
#define ITER(t, ASET, RB, BI)                                           \
  {                                                                     \
    if ((t) + 1 < nt) WRITEB((BI) ^ 1, RB);                             \
    if ((t) + 3 < nt) LOADB(RB, (t) + 3);                               \
    STEP(ASET, BI);                                                     \
    if ((t) + 2 < nt) LOADA(ASET, (t) + 2);                             \
    FENCE_BARRIER();                                                    \
  }

  // prologue: buf0 <- tile0; rB0 <- tile1; rB1 <- tile2; aset0/1 <- tiles 0/1
  LOADB(rB0, 0);
  LOADA(aset0, 0);
  LOADA(aset1, 1);
  WRITEB(0, rB0);          // one-time vmcnt stall for tile0
  LOADB(rB0, 1);
  LOADB(rB1, 2);
  FENCE_BARRIER();

  for (int t = 0; t < nt; t += 2) {
    ITER(t,     aset0, rB0, 0);
    ITER(t + 1, aset1, rB1, 1);
  }

  // adj rowsum partials: lane (l16,lhi) holds row (wrow0+rt*16+l16)'s lhi-slice.
  #pragma unroll
  for (int rt = 0; rt < 2; ++rt) {
    float s = sAcc[rt];
    s += __shfl_xor(s, 16);
    s += __shfl_xor(s, 32);
    if (l < 16) atomicAdd(&S[wrow0 + rt * 16 + l], s);
  }

  // v[i] += sum_d e[i,d]*C_part[i,d] via fragment-layout eC (coalesced 1KB frags).
  // C layout: lane(l16,lhi) reg r -> row = rt*16 + lhi*4 + r, col = ct*16 + l16.
  #pragma unroll
  for (int rt = 0; rt < 2; ++rt) {
    int R = (wrow0 >> 4) + rt;
    float p0 = 0.f, p1 = 0.f, p2 = 0.f, p3 = 0.f;
    #pragma unroll
    for (int ct = 0; ct < 8; ++ct) {
      float4 ef = *(const float4*)(eC + (((size_t)R * 8 + ct) * 64 + l) * 4);
      p0 += ef.x * acc[rt][ct][0];
      p1 += ef.y * acc[rt][ct][1];
      p2 += ef.z * acc[rt][ct][2];
      p3 += ef.w * acc[rt][ct][3];
    }
    #pragma unroll
    for (int m = 1; m < 16; m <<= 1) {
      p0 += __shfl_xor(p0, m);
      p1 += __shfl_xor(p1, m);
      p2 += __shfl_xor(p2, m);
      p3 += __shfl_xor(p3, m);
    }
    if (l16 == 0) {
      int rowb = wrow0 + rt * 16 + lhi * 4;
      atomicAdd(&v[rowb + 0], p0);
      atomicAdd(&v[rowb + 1], p1);
      atomicAdd(&v[rowb + 2], p2);
      atomicAdd(&v[rowb + 3], p3);
    }
  }
}

// Kernel 3: out = lambda * sum_i [ plp[i]*(S_i/max(S_i,eps)) - v[i]/max(S_i,eps) ]
__global__ __launch_bounds__(1024)
void final_kernel(const float* __restrict__ plp, const float* __restrict__ S,
                  const float* __restrict__ v, const float* __restrict__ lam,
                  float* __restrict__ out, int N) {
  __shared__ float red[16];
  float acc = 0.f;
  for (int i = threadIdx.x; i < N; i += 1024) {
    float s = S[i], d = fmaxf(s, EPSN);
    acc += plp[i] * (s / d) - v[i] / d;
  }
  #pragma unroll
  for (int m = 1; m < 64; m <<= 1) acc += __shfl_xor(acc, m);
  int w = threadIdx.x >> 6, l = threadIdx.x & 63;
  if (l == 0) red[w] = acc;
  __syncthreads();
  if (threadIdx.x == 0) {
    float t = 0.f;
    #pragma unroll
    for (int i = 0; i < 16; ++i) t += red[i];
    out[0] = lam[0] * t;
  }
}

extern "C" void kernel_launch(void* const* d_in, const int* in_sizes, int n_in,
                              void* d_out, int out_size, void* d_ws, size_t ws_size,
                              hipStream_t stream) {
  const float* emb = (const float*)d_in[0];
  const float* adj = (const float*)d_in[1];
  const float* lam = (const float*)d_in[2];
  int N = in_sizes[0] / 128;  // D = 128 per reference

  char* ws = (char*)d_ws;
  float* eC           = (float*)ws;                                 // N*128 f32 (C-frag layout)
  unsigned short* lpB = (unsigned short*)(ws + (size_t)N * 512);    // N*128 bf16 (B-frag layout)
  float* plp          = (float*)(ws + (size_t)N * 768);             // N f32
  float* S            = plp + N;                                    // N f32
  float* v            = S + N;                                      // N f32

  prep_kernel<<<(N + 3) / 4, 256, 0, stream>>>(emb, eC, lpB, plp, S, v, N);
  dim3 grid(N / 128, KSPLIT);
  gemm_kernel<<<grid, 256, 0, stream>>>(adj, eC, lpB, S, v, N);
  final_kernel<<<1, 1024, 0, stream>>>(plp, S, v, lam, (float*)d_out, N);
}

// Round 7
// 221.304 us; speedup vs baseline: 2.3320x; 1.1126x over previous
//
#include <hip/hip_runtime.h>
#include <hip/hip_bf16.h>

#define EPSN 1e-12f
#define EPSL 1e-10f
#define TILEM 32
#define KSPLIT 2
#define KS 256

typedef __attribute__((ext_vector_type(8))) short short8;
typedef __attribute__((ext_vector_type(4))) float f32x4;

__device__ __forceinline__ unsigned short f2bf_rne(float f) {
  union { float f; unsigned u; } x; x.f = f;
  unsigned r = x.u + 0x7FFFu + ((x.u >> 16) & 1u);
  return (unsigned short)(r >> 16);
}

// Kernel 1: per-row prep. One wave per row (D=128, 2 elems/lane).
// eC = e = x/max(||x||_4,eps) in MFMA C-fragment layout (1KB tiles).
// lpB = bf16(log(e+eps)) in MFMA B-fragment order (1KB frags).
// plp[row] = sum_d e*log_p; zero S/v.
__global__ __launch_bounds__(256)
void prep_kernel(const float* __restrict__ emb, float* __restrict__ eC,
                 unsigned short* __restrict__ lpB, float* __restrict__ plp,
                 float* __restrict__ S, float* __restrict__ v, int N) {
  int w = threadIdx.x >> 6, l = threadIdx.x & 63;
  int row = blockIdx.x * 4 + w;
  if (row >= N) return;
  const float* x = emb + (size_t)row * 128;
  float2 xv = *(const float2*)(x + 2 * l);
  float s4 = xv.x*xv.x*xv.x*xv.x + xv.y*xv.y*xv.y*xv.y;
  #pragma unroll
  for (int m = 1; m < 64; m <<= 1) s4 += __shfl_xor(s4, m);
  float denom = fmaxf(sqrtf(sqrtf(s4)), EPSN);
  float e0 = xv.x / denom, e1 = xv.y / denom;
  float lp0 = logf(e0 + EPSL), lp1 = logf(e1 + EPSL);
  int Rg = row >> 4, lhig = (row >> 2) & 3, rg = row & 3;
  int d0 = 2 * l, d1 = 2 * l + 1;
  eC[(((size_t)Rg * 8 + (d0 >> 4)) * 64 + (d0 & 15) + 16 * lhig) * 4 + rg] = e0;
  eC[(((size_t)Rg * 8 + (d1 >> 4)) * 64 + (d1 & 15) + 16 * lhig) * 4 + rg] = e1;
  int ksr = row >> 5, lhir = (row >> 3) & 3, jr = row & 7;
  lpB[((size_t)(ksr*8 + (d0>>4))*64 + (d0&15) + 16*lhir)*8 + jr] = f2bf_rne(lp0);
  lpB[((size_t)(ksr*8 + (d1>>4))*64 + (d1&15) + 16*lhir)*8 + jr] = f2bf_rne(lp1);
  float pl = e0 * lp0 + e1 * lp1;
  #pragma unroll
  for (int m = 1; m < 64; m <<= 1) pl += __shfl_xor(pl, m);
  if (l == 0) { plp[row] = pl; S[row] = 0.f; v[row] = 0.f; }
}

// Kernel 2: fused GEMM M = adj @ log_p for a 32-row tile, marching K in
// 256-k chunks. adj is read in 1KB-CONTIGUOUS per-row runs (DRAM-friendly),
// staged fp32->bf16 into XOR-swizzled LDS (dbuf); B-frags stream from
// L2-resident fragment-ordered lpB. Wave w owns output col-frags {2w, 2w+1}.
__global__ __launch_bounds__(256, 3)
void gemm_kernel(const float* __restrict__ adj, const float* __restrict__ eC,
                 const unsigned short* __restrict__ lpB,
                 float* __restrict__ S, float* __restrict__ v, int N) {
  __shared__ unsigned short ash[2][TILEM * KS];  // 2 x 16KB, 512B rows, swizzled
  int w = threadIdx.x >> 6, l = threadIdx.x & 63;
  int l16 = l & 15, lhi = l >> 4;
  int row0 = blockIdx.x * TILEM;
  int kr = N / KSPLIT;          // 6144
  int k0 = blockIdx.y * kr;
  int nt = kr / KS;             // 24

  f32x4 acc[2][2];
  #pragma unroll
  for (int i = 0; i < 2; ++i)
    #pragma unroll
    for (int j = 0; j < 2; ++j) acc[i][j] = (f32x4){0.f, 0.f, 0.f, 0.f};
  float sAcc[8];
  #pragma unroll
  for (int j = 0; j < 8; ++j) sAcc[j] = 0.f;

  // wave w stages local rows 8w..8w+7; lane l covers floats 4l..4l+3 of each
  // 256-float (1KB) row segment — one fully-contiguous 1KB instr per row.
  const float* aBase = adj + (size_t)(row0 + 8 * w) * N + k0 + 4 * l;
  float4 ar[8];

#define LOADA(t)                                                        \
  {                                                                     \
    _Pragma("unroll")                                                   \
    for (int j_ = 0; j_ < 8; ++j_)                                      \
      ar[j_] = *(const float4*)(aBase + (size_t)j_ * N + (size_t)(t) * KS); \
  }

  // cvt + fused rowsum + swizzled LDS write (row rl: byte ^= (rl&7)<<4)
#define STAGE(bi)                                                       \
  {                                                                     \
    char* base_ = (char*)ash[bi];                                       \
    _Pragma("unroll")                                                   \
    for (int j_ = 0; j_ < 8; ++j_) {                                    \
      float4 x_ = ar[j_];                                               \
      sAcc[j_] += (x_.x + x_.y) + (x_.z + x_.w);                        \
      unsigned p0_ = (unsigned)f2bf_rne(x_.x) | ((unsigned)f2bf_rne(x_.y) << 16); \
      unsigned p1_ = (unsigned)f2bf_rne(x_.z) | ((unsigned)f2bf_rne(x_.w) << 16); \
      int rl_ = 8 * w + j_;                                             \
      int off_ = rl_ * 512 + ((l * 8) ^ ((rl_ & 7) << 4));              \
      *(uint2*)(base_ + off_) = make_uint2(p0_, p1_);                   \
    }                                                                   \
  }

#define MSTEP(bi, t)                                                    \
  {                                                                     \
    const char* base_ = (const char*)ash[bi];                           \
    size_t fb_ = (size_t)((k0 + (t) * KS) >> 5) * 8;                    \
    _Pragma("unroll")                                                   \
    for (int kg_ = 0; kg_ < 8; ++kg_) {                                 \
      int ao_ = (kg_ * 64 + lhi * 16) ^ ((l16 & 7) << 4);               \
      short8 a0_ = *(const short8*)(base_ + l16 * 512 + ao_);           \
      short8 a1_ = *(const short8*)(base_ + (16 + l16) * 512 + ao_);    \
      short8 b0_ = ((const short8*)lpB)[(fb_ + (size_t)kg_ * 8 + 2 * w) * 64 + l];     \
      short8 b1_ = ((const short8*)lpB)[(fb_ + (size_t)kg_ * 8 + 2 * w + 1) * 64 + l]; \
      acc[0][0] = __builtin_amdgcn_mfma_f32_16x16x32_bf16(a0_, b0_, acc[0][0], 0, 0, 0); \
      acc[0][1] = __builtin_amdgcn_mfma_f32_16x16x32_bf16(a0_, b1_, acc[0][1], 0, 0, 0); \
      acc[1][0] = __builtin_amdgcn_mfma_f32_16x16x32_bf16(a1_, b0_, acc[1][0], 0, 0, 0); \
      acc[1][1] = __builtin_amdgcn_mfma_f32_16x16x32_bf16(a1_, b1_, acc[1][1], 0, 0, 0); \
    }                                                                   \
  }

  // prologue: stage chunk 0
  LOADA(0);
  STAGE(0);
  __syncthreads();

  for (int t = 0; t < nt; ++t) {
    if (t + 1 < nt) LOADA(t + 1);          // issue-early: 8 x 1KB contiguous
    MSTEP(t & 1, t);                        // hides the loads' latency
    if (t + 1 < nt) STAGE((t + 1) & 1);     // write-late (other LDS buffer)
    __syncthreads();
  }

  // adj rowsum: sAcc[j] -> row row0+8w+j; full-wave reduce, 1 atomic/row/block.
  #pragma unroll
  for (int j = 0; j < 8; ++j) {
    float s = sAcc[j];
    #pragma unroll
    for (int m = 1; m < 64; m <<= 1) s += __shfl_xor(s, m);
    if (l == 0) atomicAdd(&S[row0 + 8 * w + j], s);
  }

  // v[i] += sum over this wave's cols of e[i,d]*C[i,d] via fragment-layout eC.
  #pragma unroll
  for (int rt = 0; rt < 2; ++rt) {
    int R = (row0 >> 4) + rt;
    float p0 = 0.f, p1 = 0.f, p2 = 0.f, p3 = 0.f;
    #pragma unroll
    for (int c = 0; c < 2; ++c) {
      int ctg = 2 * w + c;
      float4 ef = *(const float4*)(eC + (((size_t)R * 8 + ctg) * 64 + l) * 4);
      p0 += ef.x * acc[rt][c][0];
      p1 += ef.y * acc[rt][c][1];
      p2 += ef.z * acc[rt][c][2];
      p3 += ef.w * acc[rt][c][3];
    }
    #pragma unroll
    for (int m = 1; m < 16; m <<= 1) {
      p0 += __shfl_xor(p0, m);
      p1 += __shfl_xor(p1, m);
      p2 += __shfl_xor(p2, m);
      p3 += __shfl_xor(p3, m);
    }
    if (l16 == 0) {
      int rb = row0 + rt * 16 + lhi * 4;
      atomicAdd(&v[rb + 0], p0);
      atomicAdd(&v[rb + 1], p1);
      atomicAdd(&v[rb + 2], p2);
      atomicAdd(&v[rb + 3], p3);
    }
  }
}

// Kernel 3: out = lambda * sum_i [ plp[i]*(S_i/max(S_i,eps)) - v[i]/max(S_i,eps) ]
__global__ __launch_bounds__(1024)
void final_kernel(const float* __restrict__ plp, const float* __restrict__ S,
                  const float* __restrict__ v, const float* __restrict__ lam,
                  float* __restrict__ out, int N) {
  __shared__ float red[16];
  float acc = 0.f;
  for (int i = threadIdx.x; i < N; i += 1024) {
    float s = S[i], d = fmaxf(s, EPSN);
    acc += plp[i] * (s / d) - v[i] / d;
  }
  #pragma unroll
  for (int m = 1; m < 64; m <<= 1) acc += __shfl_xor(acc, m);
  int w = threadIdx.x >> 6, l = threadIdx.x & 63;
  if (l == 0) red[w] = acc;
  __syncthreads();
  if (threadIdx.x == 0) {
    float t = 0.f;
    #pragma unroll
    for (int i = 0; i < 16; ++i) t += red[i];
    out[0] = lam[0] * t;
  }
}

extern "C" void kernel_launch(void* const* d_in, const int* in_sizes, int n_in,
                              void* d_out, int out_size, void* d_ws, size_t ws_size,
                              hipStream_t stream) {
  const float* emb = (const float*)d_in[0];
  const float* adj = (const float*)d_in[1];
  const float* lam = (const float*)d_in[2];
  int N = in_sizes[0] / 128;  // D = 128 per reference

  char* ws = (char*)d_ws;
  float* eC           = (float*)ws;                                 // N*128 f32 (C-frag layout)
  unsigned short* lpB = (unsigned short*)(ws + (size_t)N * 512);    // N*128 bf16 (B-frag layout)
  float* plp          = (float*)(ws + (size_t)N * 768);             // N f32
  float* S            = plp + N;                                    // N f32
  float* v            = S + N;                                      // N f32

  prep_kernel<<<(N + 3) / 4, 256, 0, stream>>>(emb, eC, lpB, plp, S, v, N);
  dim3 grid(N / TILEM, KSPLIT);
  gemm_kernel<<<grid, 256, 0, stream>>>(adj, eC, lpB, S, v, N);
  final_kernel<<<1, 1024, 0, stream>>>(plp, S, v, lam, (float*)d_out, N);
}

// Round 9
// 198.455 us; speedup vs baseline: 2.6005x; 1.1151x over previous
//
#include <hip/hip_runtime.h>
#include <hip/hip_bf16.h>

#define EPSN 1e-12f
#define EPSL 1e-10f
#define KSPLIT 64
#define KS 64

typedef __attribute__((ext_vector_type(8))) short short8;
typedef __attribute__((ext_vector_type(4))) float f32x4;

__device__ __forceinline__ unsigned short f2bf_rne(float f) {
  union { float f; unsigned u; } x; x.f = f;
  unsigned r = x.u + 0x7FFFu + ((x.u >> 16) & 1u);
  return (unsigned short)(r >> 16);
}

// Kernel 1: per-row prep. One wave per row (D=128, 2 elems/lane).
// eC = e = x/max(||x||_4,eps) in MFMA C-fragment layout (contiguous 1KB tiles).
// lpB = bf16(log(e+eps)) in MFMA B-fragment order (contiguous 1KB frags).
// plp[row] = sum_d e*log_p; zero S/v.
__global__ __launch_bounds__(256)
void prep_kernel(const float* __restrict__ emb, float* __restrict__ eC,
                 unsigned short* __restrict__ lpB, float* __restrict__ plp,
                 float* __restrict__ S, float* __restrict__ v, int N) {
  int w = threadIdx.x >> 6, l = threadIdx.x & 63;
  int row = blockIdx.x * 4 + w;
  if (row >= N) return;
  const float* x = emb + (size_t)row * 128;
  float2 xv = *(const float2*)(x + 2 * l);
  float s4 = xv.x*xv.x*xv.x*xv.x + xv.y*xv.y*xv.y*xv.y;
  #pragma unroll
  for (int m = 1; m < 64; m <<= 1) s4 += __shfl_xor(s4, m);
  float denom = fmaxf(sqrtf(sqrtf(s4)), EPSN);
  float e0 = xv.x / denom, e1 = xv.y / denom;
  float lp0 = logf(e0 + EPSL), lp1 = logf(e1 + EPSL);
  int Rg = row >> 4, lhig = (row >> 2) & 3, rg = row & 3;
  int d0 = 2 * l, d1 = 2 * l + 1;
  eC[(((size_t)Rg * 8 + (d0 >> 4)) * 64 + (d0 & 15) + 16 * lhig) * 4 + rg] = e0;
  eC[(((size_t)Rg * 8 + (d1 >> 4)) * 64 + (d1 & 15) + 16 * lhig) * 4 + rg] = e1;
  int ksr = row >> 5, lhir = (row >> 3) & 3, jr = row & 7;
  lpB[((size_t)(ksr*8 + (d0>>4))*64 + (d0&15) + 16*lhir)*8 + jr] = f2bf_rne(lp0);
  lpB[((size_t)(ksr*8 + (d1>>4))*64 + (d1&15) + 16*lhir)*8 + jr] = f2bf_rne(lp1);
  float pl = e0 * lp0 + e1 * lp1;
  #pragma unroll
  for (int m = 1; m < 64; m <<= 1) pl += __shfl_xor(pl, m);
  if (l == 0) { plp[row] = pl; S[row] = 0.f; v[row] = 0.f; }
}

// Kernel 2: fused GEMM M = adj @ log_p — R3 champion structure:
// B staged ONCE per block (48KB LDS, cacheable loads -> stays L2-resident),
// barrier-free K-loop, A direct-to-reg with 2-step prefetch, adj loads
// NONTEMPORAL (streaming: don't evict B from L2/L3). Fused rowsum; coalesced
// eC-fragment epilogue contraction.
__global__ __launch_bounds__(256, 2)
void gemm_kernel(const float* __restrict__ adj, const float* __restrict__ eC,
                 const unsigned short* __restrict__ lpB,
                 float* __restrict__ S, float* __restrict__ v, int N) {
  __shared__ unsigned short bsh[KS * 3 * 128];  // 192k x 128d bf16 = 48KB
  int w = threadIdx.x >> 6, l = threadIdx.x & 63;
  int l16 = l & 15, lhi = l >> 4;
  int wrow0 = blockIdx.x * 128 + w * 32;
  int kr = N / KSPLIT;          // 192
  int k0 = blockIdx.y * kr;
  int nsteps = kr / KS;         // 3

  // ---- stage B once: 48KB contiguous (frag-major), 12KB per wave ----
  {
    const short8* gB = (const short8*)(lpB + (size_t)k0 * 128);
    short8* sB = (short8*)bsh;
    #pragma unroll
    for (int i = 0; i < 12; ++i) {
      int idx = (w * 12 + i) * 64 + l;
      sB[idx] = gB[idx];
    }
  }

  f32x4 acc[2][8];
  #pragma unroll
  for (int i = 0; i < 2; ++i)
    #pragma unroll
    for (int j = 0; j < 8; ++j) acc[i][j] = (f32x4){0.f, 0.f, 0.f, 0.f};
  float sAcc[2] = {0.f, 0.f};

  // A: lane (l16,lhi) reads rows wrow0+l16 / +16, k = k0+s*64+ks*32+lhi*8 (2x f32x4)
  const float* rp0 = adj + (size_t)(wrow0 + l16) * N + k0 + lhi * 8;
  const float* rp1 = rp0 + (size_t)16 * N;

  f32x4 ra[2][2][2], rb[2][2][2];

#define LOADA(buf, s)                                                   \
  {                                                                     \
    _Pragma("unroll")                                                   \
    for (int rt_ = 0; rt_ < 2; ++rt_) {                                 \
      const float* bp_ = (rt_ ? rp1 : rp0) + (s) * KS;                  \
      _Pragma("unroll")                                                 \
      for (int ks_ = 0; ks_ < 2; ++ks_) {                               \
        buf[rt_][ks_][0] = __builtin_nontemporal_load((const f32x4*)(bp_ + ks_ * 32));     \
        buf[rt_][ks_][1] = __builtin_nontemporal_load((const f32x4*)(bp_ + ks_ * 32 + 4)); \
      }                                                                 \
    }                                                                   \
  }

#define STEP(buf, s)                                                    \
  {                                                                     \
    _Pragma("unroll")                                                   \
    for (int ks_ = 0; ks_ < 2; ++ks_) {                                 \
      short8 bb_[8];                                                    \
      _Pragma("unroll")                                                 \
      for (int ct_ = 0; ct_ < 8; ++ct_)                                 \
        bb_[ct_] = *((const short8*)bsh + ((size_t)(((s)*2 + ks_)*8 + ct_))*64 + l); \
      short8 af_[2];                                                    \
      _Pragma("unroll")                                                 \
      for (int rt_ = 0; rt_ < 2; ++rt_) {                               \
        f32x4 x0_ = buf[rt_][ks_][0], x1_ = buf[rt_][ks_][1];           \
        sAcc[rt_] += ((x0_[0] + x0_[1]) + (x0_[2] + x0_[3])) +          \
                     ((x1_[0] + x1_[1]) + (x1_[2] + x1_[3]));           \
        short8 t_;                                                      \
        t_[0] = (short)f2bf_rne(x0_[0]); t_[1] = (short)f2bf_rne(x0_[1]); \
        t_[2] = (short)f2bf_rne(x0_[2]); t_[3] = (short)f2bf_rne(x0_[3]); \
        t_[4] = (short)f2bf_rne(x1_[0]); t_[5] = (short)f2bf_rne(x1_[1]); \
        t_[6] = (short)f2bf_rne(x1_[2]); t_[7] = (short)f2bf_rne(x1_[3]); \
        af_[rt_] = t_;                                                  \
      }                                                                 \
      _Pragma("unroll")                                                 \
      for (int ct_ = 0; ct_ < 8; ++ct_) {                               \
        acc[0][ct_] = __builtin_amdgcn_mfma_f32_16x16x32_bf16(af_[0], bb_[ct_], acc[0][ct_], 0, 0, 0); \
        acc[1][ct_] = __builtin_amdgcn_mfma_f32_16x16x32_bf16(af_[1], bb_[ct_], acc[1][ct_], 0, 0, 0); \
      }                                                                 \
    }                                                                   \
  }

  LOADA(ra, 0);
  __syncthreads();  // B staged (one-time drain; no barriers in the K-loop)

  for (int s = 0; s < nsteps; s += 2) {
    if (s + 1 < nsteps) LOADA(rb, s + 1);
    STEP(ra, s);
    if (s + 2 < nsteps) LOADA(ra, s + 2);
    if (s + 1 < nsteps) STEP(rb, s + 1);
  }

  // adj rowsum partials: lane (l16,lhi) holds row (wrow0+rt*16+l16)'s lhi-slice.
  #pragma unroll
  for (int rt = 0; rt < 2; ++rt) {
    float s = sAcc[rt];
    s += __shfl_xor(s, 16);
    s += __shfl_xor(s, 32);
    if (l < 16) atomicAdd(&S[wrow0 + rt * 16 + l], s);
  }

  // v[i] += sum_d e[i,d]*C_part[i,d] via fragment-layout eC (coalesced 1KB frags).
  // C layout: lane(l16,lhi) reg r -> row = rt*16 + lhi*4 + r, col = ct*16 + l16.
  #pragma unroll
  for (int rt = 0; rt < 2; ++rt) {
    int R = (wrow0 >> 4) + rt;
    float p0 = 0.f, p1 = 0.f, p2 = 0.f, p3 = 0.f;
    #pragma unroll
    for (int ct = 0; ct < 8; ++ct) {
      f32x4 ef = *(const f32x4*)(eC + (((size_t)R * 8 + ct) * 64 + l) * 4);
      p0 += ef[0] * acc[rt][ct][0];
      p1 += ef[1] * acc[rt][ct][1];
      p2 += ef[2] * acc[rt][ct][2];
      p3 += ef[3] * acc[rt][ct][3];
    }
    #pragma unroll
    for (int m = 1; m < 16; m <<= 1) {
      p0 += __shfl_xor(p0, m);
      p1 += __shfl_xor(p1, m);
      p2 += __shfl_xor(p2, m);
      p3 += __shfl_xor(p3, m);
    }
    if (l16 == 0) {
      int rowb = wrow0 + rt * 16 + lhi * 4;
      atomicAdd(&v[rowb + 0], p0);
      atomicAdd(&v[rowb + 1], p1);
      atomicAdd(&v[rowb + 2], p2);
      atomicAdd(&v[rowb + 3], p3);
    }
  }
}

// Kernel 3: out = lambda * sum_i [ plp[i]*(S_i/max(S_i,eps)) - v[i]/max(S_i,eps) ]
__global__ __launch_bounds__(1024)
void final_kernel(const float* __restrict__ plp, const float* __restrict__ S,
                  const float* __restrict__ v, const float* __restrict__ lam,
                  float* __restrict__ out, int N) {
  __shared__ float red[16];
  float acc = 0.f;
  for (int i = threadIdx.x; i < N; i += 1024) {
    float s = S[i], d = fmaxf(s, EPSN);
    acc += plp[i] * (s / d) - v[i] / d;
  }
  #pragma unroll
  for (int m = 1; m < 64; m <<= 1) acc += __shfl_xor(acc, m);
  int w = threadIdx.x >> 6, l = threadIdx.x & 63;
  if (l == 0) red[w] = acc;
  __syncthreads();
  if (threadIdx.x == 0) {
    float t = 0.f;
    #pragma unroll
    for (int i = 0; i < 16; ++i) t += red[i];
    out[0] = lam[0] * t;
  }
}

extern "C" void kernel_launch(void* const* d_in, const int* in_sizes, int n_in,
                              void* d_out, int out_size, void* d_ws, size_t ws_size,
                              hipStream_t stream) {
  const float* emb = (const float*)d_in[0];
  const float* adj = (const float*)d_in[1];
  const float* lam = (const float*)d_in[2];
  int N = in_sizes[0] / 128;  // D = 128 per reference

  char* ws = (char*)d_ws;
  float* eC           = (float*)ws;                                 // N*128 f32 (C-frag layout)
  unsigned short* lpB = (unsigned short*)(ws + (size_t)N * 512);    // N*128 bf16 (B-frag layout)
  float* plp          = (float*)(ws + (size_t)N * 768);             // N f32
  float* S            = plp + N;                                    // N f32
  float* v            = S + N;                                      // N f32

  prep_kernel<<<(N + 3) / 4, 256, 0, stream>>>(emb, eC, lpB, plp, S, v, N);
  dim3 grid(N / 128, KSPLIT);
  gemm_kernel<<<grid, 256, 0, stream>>>(adj, eC, lpB, S, v, N);
  final_kernel<<<1, 1024, 0, stream>>>(plp, S, v, lam, (float*)d_out, N);
}